// Round 7
// baseline (481.679 us; speedup 1.0000x reference)
//
#include <hip/hip_runtime.h>
#include <hip/hip_bf16.h>
#include <math.h>

// Problem dims (fixed): T=512, B=256, I=128, H=256
#define TT 512
#define BB 256
#define II 128
#define HH 256

typedef float f4 __attribute__((ext_vector_type(4)));

// ---------------------------------------------------------------------------
// Kernel 1: input projection  xi[m][n] = sum_k x[m][k]*Wi[n][k] + bh[n]
//   M = T*B = 131072, K = 128, N = 256. Written into d_out (later overwritten
//   in-place by the recurrence with h_t).
// ---------------------------------------------------------------------------
__global__ __launch_bounds__(256) void proj_kernel(
    const float* __restrict__ x, const float* __restrict__ Wi,
    const float* __restrict__ bh, float* __restrict__ out)
{
    __shared__ float xt[128][68];
    __shared__ float wt[128][64];

    const int tid = threadIdx.x;
    const int m0 = blockIdx.x * 64;
    const int j0 = blockIdx.y * 64;

    {
        const int r  = tid & 63;
        const int kc = tid >> 6;
        const float* xsrc = x  + (size_t)(m0 + r) * II + kc * 32;
        const float* wsrc = Wi + (size_t)(j0 + r) * II + kc * 32;
#pragma unroll
        for (int u = 0; u < 8; ++u) {
            float4 v = *(const float4*)(xsrc + u * 4);
            int k = kc * 32 + u * 4;
            xt[k + 0][r] = v.x; xt[k + 1][r] = v.y;
            xt[k + 2][r] = v.z; xt[k + 3][r] = v.w;
        }
#pragma unroll
        for (int u = 0; u < 8; ++u) {
            float4 v = *(const float4*)(wsrc + u * 4);
            int k = kc * 32 + u * 4;
            wt[k + 0][r] = v.x; wt[k + 1][r] = v.y;
            wt[k + 2][r] = v.z; wt[k + 3][r] = v.w;
        }
    }
    __syncthreads();

    const int ty = tid >> 4, tx = tid & 15;
    const int r0 = ty * 4, c0 = tx * 4;
    float acc[4][4] = {};
#pragma unroll 4
    for (int k = 0; k < 128; ++k) {
        float4 a = *(const float4*)&xt[k][r0];
        float4 b = *(const float4*)&wt[k][c0];
        float av[4] = {a.x, a.y, a.z, a.w};
        float bv[4] = {b.x, b.y, b.z, b.w};
#pragma unroll
        for (int i = 0; i < 4; ++i)
#pragma unroll
            for (int j = 0; j < 4; ++j)
                acc[i][j] += av[i] * bv[j];
    }

    float4 bias = *(const float4*)(bh + j0 + c0);
    float bvv[4] = {bias.x, bias.y, bias.z, bias.w};
#pragma unroll
    for (int i = 0; i < 4; ++i) {
        float4 o;
        o.x = acc[i][0] + bvv[0];
        o.y = acc[i][1] + bvv[1];
        o.z = acc[i][2] + bvv[2];
        o.w = acc[i][3] + bvv[3];
        *(float4*)(out + (size_t)(m0 + r0 + i) * HH + j0 + c0) = o;
    }
}

// ---------------------------------------------------------------------------
// Kernel 2: recurrence, full inline-asm time loop, ONE barrier per step.
// 512 threads = 8 waves, 1 block per batch row.
//   Thread = 1 column x 128 k: col = 32*wave + (lane&31), khalf = lane>>5.
//   Wh fragment = Wh[col][khalf*128 .. +128) = contiguous 512B = 32 f4
//   pinned in v72-v199 (asm-owned; compiler can't spill — r1-r5 lesson).
//   Cross-k reduce = 7 reg adds + ONE ds_bpermute (lane <-> lane^32):
//   no partials array, no reduce phase, no second barrier.
//   h double-buffered in LDS (2x256 f, XOR 0x400/step): write buf^1 before
//   the single barrier, read buf after — race-free with 1 barrier.
//   hv pipeline: 12 quads (3 chunks) in flight, counted lgkmcnt(8) waits
//   (r6 had depth-1-chunk => ~90cyc stall/chunk).
//   Register map: v24 hv-read base, v25 h-write addr, v26 xi, v28/v29 temps,
//   v[32:39] 4 acc pairs, v40-71 + v200-215 hv slots (12 quads),
//   v72-v199 Wh fragment. VGPR 216 -> 2 waves/SIMD.
// ---------------------------------------------------------------------------
__global__ __launch_bounds__(512, 2) void rec_kernel(
    const float* __restrict__ Wh, const float* __restrict__ h0,
    float* __restrict__ io)
{
    __shared__ float h2[2][HH];   // double-buffered h, 2 KB

    const int tid  = threadIdx.x;
    const int b    = blockIdx.x;
    const int lane = tid & 63;
    const int q    = tid >> 6;           // wave id 0..7
    const int col  = q * 32 + (lane & 31);
    const int kh   = lane >> 5;          // k-half 0/1

    const float* wp  = Wh + (size_t)col * HH + kh * 128;  // 512B contiguous
    const float* iob = io + (size_t)b * HH;
    unsigned vio  = (unsigned)(col * 4);                  // byte voffset
    unsigned hbase = (unsigned)(size_t)&h2[0][0];
    unsigned hb0  = hbase + kh * 512;          // read base, buffer 0
    unsigned hw1  = hbase + 0x400 + col * 4;   // write addr, buffer 1
    unsigned ba   = (unsigned)((lane ^ 32) << 2); // bpermute addr

    if (tid < HH) h2[0][tid] = h0[(size_t)b * HH + tid];
    __syncthreads();

    asm volatile(
        // ---- Wh fragment: 32x dwordx4, contiguous 512B ----
        "global_load_dwordx4 v[72:75],   %[wp], off\n"
        "global_load_dwordx4 v[76:79],   %[wp], off offset:16\n"
        "global_load_dwordx4 v[80:83],   %[wp], off offset:32\n"
        "global_load_dwordx4 v[84:87],   %[wp], off offset:48\n"
        "global_load_dwordx4 v[88:91],   %[wp], off offset:64\n"
        "global_load_dwordx4 v[92:95],   %[wp], off offset:80\n"
        "global_load_dwordx4 v[96:99],   %[wp], off offset:96\n"
        "global_load_dwordx4 v[100:103], %[wp], off offset:112\n"
        "global_load_dwordx4 v[104:107], %[wp], off offset:128\n"
        "global_load_dwordx4 v[108:111], %[wp], off offset:144\n"
        "global_load_dwordx4 v[112:115], %[wp], off offset:160\n"
        "global_load_dwordx4 v[116:119], %[wp], off offset:176\n"
        "global_load_dwordx4 v[120:123], %[wp], off offset:192\n"
        "global_load_dwordx4 v[124:127], %[wp], off offset:208\n"
        "global_load_dwordx4 v[128:131], %[wp], off offset:224\n"
        "global_load_dwordx4 v[132:135], %[wp], off offset:240\n"
        "global_load_dwordx4 v[136:139], %[wp], off offset:256\n"
        "global_load_dwordx4 v[140:143], %[wp], off offset:272\n"
        "global_load_dwordx4 v[144:147], %[wp], off offset:288\n"
        "global_load_dwordx4 v[148:151], %[wp], off offset:304\n"
        "global_load_dwordx4 v[152:155], %[wp], off offset:320\n"
        "global_load_dwordx4 v[156:159], %[wp], off offset:336\n"
        "global_load_dwordx4 v[160:163], %[wp], off offset:352\n"
        "global_load_dwordx4 v[164:167], %[wp], off offset:368\n"
        "global_load_dwordx4 v[168:171], %[wp], off offset:384\n"
        "global_load_dwordx4 v[172:175], %[wp], off offset:400\n"
        "global_load_dwordx4 v[176:179], %[wp], off offset:416\n"
        "global_load_dwordx4 v[180:183], %[wp], off offset:432\n"
        "global_load_dwordx4 v[184:187], %[wp], off offset:448\n"
        "global_load_dwordx4 v[188:191], %[wp], off offset:464\n"
        "global_load_dwordx4 v[192:195], %[wp], off offset:480\n"
        "global_load_dwordx4 v[196:199], %[wp], off offset:496\n"
        // ---- init ----
        "v_mov_b32 v24, %[hb0]\n"
        "v_mov_b32 v25, %[hw1]\n"
        "s_mov_b32 s80, -1\n"
        "s_mov_b32 s81, 0\n"
        "s_movk_i32 s82, 0x200\n"
        "s_waitcnt vmcnt(0)\n"
        "LTOP_%=:\n"
        // ---- xi load (all lanes, dup x2 across halves) ----
        "global_load_dword v26, %[vio], %[iob]\n"
        // ---- hv prologue: 12 quads = chunks 0,1,2 ----
        "ds_read_b128 v[40:43],   v24\n"
        "ds_read_b128 v[44:47],   v24 offset:16\n"
        "ds_read_b128 v[48:51],   v24 offset:32\n"
        "ds_read_b128 v[52:55],   v24 offset:48\n"
        "ds_read_b128 v[56:59],   v24 offset:64\n"
        "ds_read_b128 v[60:63],   v24 offset:80\n"
        "ds_read_b128 v[64:67],   v24 offset:96\n"
        "ds_read_b128 v[68:71],   v24 offset:112\n"
        "ds_read_b128 v[200:203], v24 offset:128\n"
        "ds_read_b128 v[204:207], v24 offset:144\n"
        "ds_read_b128 v[208:211], v24 offset:160\n"
        "ds_read_b128 v[212:215], v24 offset:176\n"
        // ---- chunk 0: w v72-87, slots v40-55; reissue chunk3 ----
        "s_waitcnt lgkmcnt(8)\n"
        "v_pk_mul_f32 v[32:33], v[72:73], v[40:41]\n"
        "v_pk_mul_f32 v[34:35], v[74:75], v[42:43]\n"
        "v_pk_mul_f32 v[36:37], v[76:77], v[44:45]\n"
        "v_pk_mul_f32 v[38:39], v[78:79], v[46:47]\n"
        "v_pk_fma_f32 v[32:33], v[80:81], v[48:49], v[32:33]\n"
        "v_pk_fma_f32 v[34:35], v[82:83], v[50:51], v[34:35]\n"
        "v_pk_fma_f32 v[36:37], v[84:85], v[52:53], v[36:37]\n"
        "v_pk_fma_f32 v[38:39], v[86:87], v[54:55], v[38:39]\n"
        "ds_read_b128 v[40:43], v24 offset:192\n"
        "ds_read_b128 v[44:47], v24 offset:208\n"
        "ds_read_b128 v[48:51], v24 offset:224\n"
        "ds_read_b128 v[52:55], v24 offset:240\n"
        // ---- chunk 1: w v88-103, slots v56-71; reissue chunk4 ----
        "s_waitcnt lgkmcnt(8)\n"
        "v_pk_fma_f32 v[32:33], v[88:89],   v[56:57], v[32:33]\n"
        "v_pk_fma_f32 v[34:35], v[90:91],   v[58:59], v[34:35]\n"
        "v_pk_fma_f32 v[36:37], v[92:93],   v[60:61], v[36:37]\n"
        "v_pk_fma_f32 v[38:39], v[94:95],   v[62:63], v[38:39]\n"
        "v_pk_fma_f32 v[32:33], v[96:97],   v[64:65], v[32:33]\n"
        "v_pk_fma_f32 v[34:35], v[98:99],   v[66:67], v[34:35]\n"
        "v_pk_fma_f32 v[36:37], v[100:101], v[68:69], v[36:37]\n"
        "v_pk_fma_f32 v[38:39], v[102:103], v[70:71], v[38:39]\n"
        "ds_read_b128 v[56:59], v24 offset:256\n"
        "ds_read_b128 v[60:63], v24 offset:272\n"
        "ds_read_b128 v[64:67], v24 offset:288\n"
        "ds_read_b128 v[68:71], v24 offset:304\n"
        // ---- chunk 2: w v104-119, slots v200-215; reissue chunk5 ----
        "s_waitcnt lgkmcnt(8)\n"
        "v_pk_fma_f32 v[32:33], v[104:105], v[200:201], v[32:33]\n"
        "v_pk_fma_f32 v[34:35], v[106:107], v[202:203], v[34:35]\n"
        "v_pk_fma_f32 v[36:37], v[108:109], v[204:205], v[36:37]\n"
        "v_pk_fma_f32 v[38:39], v[110:111], v[206:207], v[38:39]\n"
        "v_pk_fma_f32 v[32:33], v[112:113], v[208:209], v[32:33]\n"
        "v_pk_fma_f32 v[34:35], v[114:115], v[210:211], v[34:35]\n"
        "v_pk_fma_f32 v[36:37], v[116:117], v[212:213], v[36:37]\n"
        "v_pk_fma_f32 v[38:39], v[118:119], v[214:215], v[38:39]\n"
        "ds_read_b128 v[200:203], v24 offset:320\n"
        "ds_read_b128 v[204:207], v24 offset:336\n"
        "ds_read_b128 v[208:211], v24 offset:352\n"
        "ds_read_b128 v[212:215], v24 offset:368\n"
        // ---- chunk 3: w v120-135, slots v40-55; reissue chunk6 ----
        "s_waitcnt lgkmcnt(8)\n"
        "v_pk_fma_f32 v[32:33], v[120:121], v[40:41], v[32:33]\n"
        "v_pk_fma_f32 v[34:35], v[122:123], v[42:43], v[34:35]\n"
        "v_pk_fma_f32 v[36:37], v[124:125], v[44:45], v[36:37]\n"
        "v_pk_fma_f32 v[38:39], v[126:127], v[46:47], v[38:39]\n"
        "v_pk_fma_f32 v[32:33], v[128:129], v[48:49], v[32:33]\n"
        "v_pk_fma_f32 v[34:35], v[130:131], v[50:51], v[34:35]\n"
        "v_pk_fma_f32 v[36:37], v[132:133], v[52:53], v[36:37]\n"
        "v_pk_fma_f32 v[38:39], v[134:135], v[54:55], v[38:39]\n"
        "ds_read_b128 v[40:43], v24 offset:384\n"
        "ds_read_b128 v[44:47], v24 offset:400\n"
        "ds_read_b128 v[48:51], v24 offset:416\n"
        "ds_read_b128 v[52:55], v24 offset:432\n"
        // ---- chunk 4: w v136-151, slots v56-71; reissue chunk7 ----
        "s_waitcnt lgkmcnt(8)\n"
        "v_pk_fma_f32 v[32:33], v[136:137], v[56:57], v[32:33]\n"
        "v_pk_fma_f32 v[34:35], v[138:139], v[58:59], v[34:35]\n"
        "v_pk_fma_f32 v[36:37], v[140:141], v[60:61], v[36:37]\n"
        "v_pk_fma_f32 v[38:39], v[142:143], v[62:63], v[38:39]\n"
        "v_pk_fma_f32 v[32:33], v[144:145], v[64:65], v[32:33]\n"
        "v_pk_fma_f32 v[34:35], v[146:147], v[66:67], v[34:35]\n"
        "v_pk_fma_f32 v[36:37], v[148:149], v[68:69], v[36:37]\n"
        "v_pk_fma_f32 v[38:39], v[150:151], v[70:71], v[38:39]\n"
        "ds_read_b128 v[56:59], v24 offset:448\n"
        "ds_read_b128 v[60:63], v24 offset:464\n"
        "ds_read_b128 v[64:67], v24 offset:480\n"
        "ds_read_b128 v[68:71], v24 offset:496\n"
        // ---- chunk 5: w v152-167, slots v200-215 ----
        "s_waitcnt lgkmcnt(8)\n"
        "v_pk_fma_f32 v[32:33], v[152:153], v[200:201], v[32:33]\n"
        "v_pk_fma_f32 v[34:35], v[154:155], v[202:203], v[34:35]\n"
        "v_pk_fma_f32 v[36:37], v[156:157], v[204:205], v[36:37]\n"
        "v_pk_fma_f32 v[38:39], v[158:159], v[206:207], v[38:39]\n"
        "v_pk_fma_f32 v[32:33], v[160:161], v[208:209], v[32:33]\n"
        "v_pk_fma_f32 v[34:35], v[162:163], v[210:211], v[34:35]\n"
        "v_pk_fma_f32 v[36:37], v[164:165], v[212:213], v[36:37]\n"
        "v_pk_fma_f32 v[38:39], v[166:167], v[214:215], v[38:39]\n"
        // ---- chunk 6: w v168-183, slots v40-55 ----
        "s_waitcnt lgkmcnt(4)\n"
        "v_pk_fma_f32 v[32:33], v[168:169], v[40:41], v[32:33]\n"
        "v_pk_fma_f32 v[34:35], v[170:171], v[42:43], v[34:35]\n"
        "v_pk_fma_f32 v[36:37], v[172:173], v[44:45], v[36:37]\n"
        "v_pk_fma_f32 v[38:39], v[174:175], v[46:47], v[38:39]\n"
        "v_pk_fma_f32 v[32:33], v[176:177], v[48:49], v[32:33]\n"
        "v_pk_fma_f32 v[34:35], v[178:179], v[50:51], v[34:35]\n"
        "v_pk_fma_f32 v[36:37], v[180:181], v[52:53], v[36:37]\n"
        "v_pk_fma_f32 v[38:39], v[182:183], v[54:55], v[38:39]\n"
        // ---- chunk 7: w v184-199, slots v56-71 ----
        "s_waitcnt lgkmcnt(0)\n"
        "v_pk_fma_f32 v[32:33], v[184:185], v[56:57], v[32:33]\n"
        "v_pk_fma_f32 v[34:35], v[186:187], v[58:59], v[34:35]\n"
        "v_pk_fma_f32 v[36:37], v[188:189], v[60:61], v[36:37]\n"
        "v_pk_fma_f32 v[38:39], v[190:191], v[62:63], v[38:39]\n"
        "v_pk_fma_f32 v[32:33], v[192:193], v[64:65], v[32:33]\n"
        "v_pk_fma_f32 v[34:35], v[194:195], v[66:67], v[34:35]\n"
        "v_pk_fma_f32 v[36:37], v[196:197], v[68:69], v[36:37]\n"
        "v_pk_fma_f32 v[38:39], v[198:199], v[70:71], v[38:39]\n"
        // ---- reduce: 7 adds + cross-half bpermute ----
        "v_add_f32 v32, v32, v33\n"
        "v_add_f32 v34, v34, v35\n"
        "v_add_f32 v36, v36, v37\n"
        "v_add_f32 v38, v38, v39\n"
        "v_add_f32 v32, v32, v34\n"
        "v_add_f32 v36, v36, v38\n"
        "v_add_f32 v32, v32, v36\n"
        "ds_bpermute_b32 v28, %[ba], v32\n"
        "s_waitcnt vmcnt(0)\n"          // xi (issued ~600cyc ago)
        "s_waitcnt lgkmcnt(0)\n"        // bpermute
        "v_add_f32 v32, v32, v28\n"
        "v_add_f32 v32, v32, v26\n"     // + xi
        // ---- tanh = 1 - 2/(exp2(x*2log2e)+1) ----
        "v_mul_f32 v29, 0x4038aa3b, v32\n"
        "v_exp_f32 v29, v29\n"
        "s_nop 1\n"
        "v_add_f32 v29, 1.0, v29\n"
        "v_rcp_f32 v29, v29\n"
        "s_nop 1\n"
        "v_fma_f32 v32, -2.0, v29, 1.0\n"
        // ---- store h (lanes<32): LDS next-buffer + global ----
        "s_and_saveexec_b64 s[84:85], s[80:81]\n"
        "ds_write_b32 v25, v32\n"
        "global_store_dword %[vio], v32, %[iob]\n"
        "s_mov_b64 exec, s[84:85]\n"
        "s_waitcnt lgkmcnt(0)\n"
        "s_barrier\n"
        // ---- toggle buffers, advance ----
        "v_xor_b32 v24, 0x400, v24\n"
        "v_xor_b32 v25, 0x400, v25\n"
        "v_add_u32 %[vio], 0x40000, %[vio]\n"
        "s_sub_u32 s82, s82, 1\n"
        "s_cmp_lg_u32 s82, 0\n"
        "s_cbranch_scc1 LTOP_%=\n"
        : [vio] "+v"(vio)
        : [wp] "v"(wp), [iob] "s"(iob), [hb0] "v"(hb0), [hw1] "v"(hw1),
          [ba] "v"(ba)
        : "memory", "scc", "s80", "s81", "s82", "s83", "s84", "s85",
          "v24","v25","v26","v27","v28","v29","v30","v31",
          "v32","v33","v34","v35","v36","v37","v38","v39",
          "v40","v41","v42","v43","v44","v45","v46","v47",
          "v48","v49","v50","v51","v52","v53","v54","v55",
          "v56","v57","v58","v59","v60","v61","v62","v63",
          "v64","v65","v66","v67","v68","v69","v70","v71",
          "v72","v73","v74","v75","v76","v77","v78","v79",
          "v80","v81","v82","v83","v84","v85","v86","v87",
          "v88","v89","v90","v91","v92","v93","v94","v95",
          "v96","v97","v98","v99","v100","v101","v102","v103",
          "v104","v105","v106","v107","v108","v109","v110","v111",
          "v112","v113","v114","v115","v116","v117","v118","v119",
          "v120","v121","v122","v123","v124","v125","v126","v127",
          "v128","v129","v130","v131","v132","v133","v134","v135",
          "v136","v137","v138","v139","v140","v141","v142","v143",
          "v144","v145","v146","v147","v148","v149","v150","v151",
          "v152","v153","v154","v155","v156","v157","v158","v159",
          "v160","v161","v162","v163","v164","v165","v166","v167",
          "v168","v169","v170","v171","v172","v173","v174","v175",
          "v176","v177","v178","v179","v180","v181","v182","v183",
          "v184","v185","v186","v187","v188","v189","v190","v191",
          "v192","v193","v194","v195","v196","v197","v198","v199",
          "v200","v201","v202","v203","v204","v205","v206","v207",
          "v208","v209","v210","v211","v212","v213","v214","v215");
}

extern "C" void kernel_launch(void* const* d_in, const int* in_sizes, int n_in,
                              void* d_out, int out_size, void* d_ws, size_t ws_size,
                              hipStream_t stream) {
    const float* x  = (const float*)d_in[0];  // [T,B,I]
    const float* h0 = (const float*)d_in[1];  // [B,H]
    const float* Wi = (const float*)d_in[2];  // [H,I]
    const float* Wh = (const float*)d_in[3];  // [H,H]
    const float* bh = (const float*)d_in[4];  // [H]
    float* out = (float*)d_out;               // [T,B,H]

    dim3 pgrid(TT * BB / 64, HH / 64);
    proj_kernel<<<pgrid, 256, 0, stream>>>(x, Wi, bh, out);
    rec_kernel<<<BB, 512, 0, stream>>>(Wh, h0, out);
}

// Round 8
// 435.128 us; speedup vs baseline: 1.1070x; 1.1070x over previous
//
#include <hip/hip_runtime.h>
#include <hip/hip_bf16.h>
#include <math.h>

// Problem dims (fixed): T=512, B=256, I=128, H=256
#define TT 512
#define BB 256
#define II 128
#define HH 256

typedef float f4 __attribute__((ext_vector_type(4)));

// ---------------------------------------------------------------------------
// Kernel 1: input projection  xi[m][n] = sum_k x[m][k]*Wi[n][k] + bh[n]
// ---------------------------------------------------------------------------
__global__ __launch_bounds__(256) void proj_kernel(
    const float* __restrict__ x, const float* __restrict__ Wi,
    const float* __restrict__ bh, float* __restrict__ out)
{
    __shared__ float xt[128][68];
    __shared__ float wt[128][64];

    const int tid = threadIdx.x;
    const int m0 = blockIdx.x * 64;
    const int j0 = blockIdx.y * 64;

    {
        const int r  = tid & 63;
        const int kc = tid >> 6;
        const float* xsrc = x  + (size_t)(m0 + r) * II + kc * 32;
        const float* wsrc = Wi + (size_t)(j0 + r) * II + kc * 32;
#pragma unroll
        for (int u = 0; u < 8; ++u) {
            float4 v = *(const float4*)(xsrc + u * 4);
            int k = kc * 32 + u * 4;
            xt[k + 0][r] = v.x; xt[k + 1][r] = v.y;
            xt[k + 2][r] = v.z; xt[k + 3][r] = v.w;
        }
#pragma unroll
        for (int u = 0; u < 8; ++u) {
            float4 v = *(const float4*)(wsrc + u * 4);
            int k = kc * 32 + u * 4;
            wt[k + 0][r] = v.x; wt[k + 1][r] = v.y;
            wt[k + 2][r] = v.z; wt[k + 3][r] = v.w;
        }
    }
    __syncthreads();

    const int ty = tid >> 4, tx = tid & 15;
    const int r0 = ty * 4, c0 = tx * 4;
    float acc[4][4] = {};
#pragma unroll 4
    for (int k = 0; k < 128; ++k) {
        float4 a = *(const float4*)&xt[k][r0];
        float4 b = *(const float4*)&wt[k][c0];
        float av[4] = {a.x, a.y, a.z, a.w};
        float bv[4] = {b.x, b.y, b.z, b.w};
#pragma unroll
        for (int i = 0; i < 4; ++i)
#pragma unroll
            for (int j = 0; j < 4; ++j)
                acc[i][j] += av[i] * bv[j];
    }

    float4 bias = *(const float4*)(bh + j0 + c0);
    float bvv[4] = {bias.x, bias.y, bias.z, bias.w};
#pragma unroll
    for (int i = 0; i < 4; ++i) {
        float4 o;
        o.x = acc[i][0] + bvv[0];
        o.y = acc[i][1] + bvv[1];
        o.z = acc[i][2] + bvv[2];
        o.w = acc[i][3] + bvv[3];
        *(float4*)(out + (size_t)(m0 + r0 + i) * HH + j0 + c0) = o;
    }
}

// ---------------------------------------------------------------------------
// Kernel 2: recurrence, full inline-asm time loop, ONE barrier per step,
// minimal LDS traffic + pure-DPP cross-k reduction.
//
// 512 threads = 8 waves, 1 block per batch row.
//   Wave q owns cols [32q, 32q+32). Lane l:
//     kg  = (l&3)|((l>>1)&4)        (k-group, lane bits 0,1,3)
//     c_g = ((l>>2)&1)|((l>>3)&6)   (col-group, lane bits 2,4,5)
//     cols = 32q+4*c_g .. +3,  k in [32*kg, 32*kg+32)
//   Wh fragment: 4 cols x 32 k = 128 floats, v72-v199 (asm-pinned).
//   h in LDS, PADDED: kg-group g at byte g*144 (stride 36 banks) so the 8
//   broadcast ds_read_b128 addresses hit disjoint banks (linear layout
//   would be 8-way conflict: kg*128B = same bank group).  Double-buffered
//   at +0x800, one barrier/step (r7-proven pattern).
//   LDS reads: 8 b128/wave/step (=r6's minimum; r7's 32/wave was the
//   regression).  Cross-k reduce: butterfly xor1/xor2/xor8 = quad_perm
//   [1,0,3,2], [2,3,0,1], row_ror:8 — all VALU DPP, no LDS, no partials
//   array, no second barrier.
//   xi: per-lane dwordx4 at step top (all lanes, 8x dup, coalesced),
//   vmcnt(0) waited ~600cyc later (also drains prev step's h store).
//   Stores (LDS h next-buffer + global h) exec-masked to kg==0 lanes.
// ---------------------------------------------------------------------------
__global__ __launch_bounds__(512, 2) void rec_kernel(
    const float* __restrict__ Wh, const float* __restrict__ h0,
    float* __restrict__ io)
{
    __shared__ float hbuf[800];   // 2 buffers: bytes [0,1152) and [0x800,+1152)

    const int tid  = threadIdx.x;
    const int b    = blockIdx.x;
    const int lane = tid & 63;
    const int q    = tid >> 6;                       // wave id 0..7
    const int kg   = (lane & 3) | ((lane >> 1) & 4); // 0..7
    const int cg   = ((lane >> 2) & 1) | ((lane >> 3) & 6); // 0..7
    const int col0 = 32 * q + 4 * cg;

    const float* wp  = Wh + (size_t)col0 * HH + kg * 32; // 4 rows, stride 1KB
    const float* iob = io + (size_t)b * HH;
    unsigned hbase = (unsigned)(size_t)&hbuf[0];
    unsigned hvr = hbase + kg * 144;                  // read base (buf 0)
    unsigned hvw = hbase + 0x800 + q * 144 + cg * 16; // write addr (buf 1)
    unsigned vio = (unsigned)(col0 * 4);              // io byte offset
    unsigned long long msk = __ballot(kg == 0);       // finalizer lanes

    if (tid < HH) hbuf[(tid >> 5) * 36 + (tid & 31)] = h0[(size_t)b * HH + tid];
    __syncthreads();

    asm volatile(
        // ---- Wh fragment: w[j][m] -> v[72+32j+4m], j=row, m=k-quad ----
        "global_load_dwordx4 v[72:75],   %[wp], off\n"
        "global_load_dwordx4 v[76:79],   %[wp], off offset:16\n"
        "global_load_dwordx4 v[80:83],   %[wp], off offset:32\n"
        "global_load_dwordx4 v[84:87],   %[wp], off offset:48\n"
        "global_load_dwordx4 v[88:91],   %[wp], off offset:64\n"
        "global_load_dwordx4 v[92:95],   %[wp], off offset:80\n"
        "global_load_dwordx4 v[96:99],   %[wp], off offset:96\n"
        "global_load_dwordx4 v[100:103], %[wp], off offset:112\n"
        "global_load_dwordx4 v[104:107], %[wp], off offset:1024\n"
        "global_load_dwordx4 v[108:111], %[wp], off offset:1040\n"
        "global_load_dwordx4 v[112:115], %[wp], off offset:1056\n"
        "global_load_dwordx4 v[116:119], %[wp], off offset:1072\n"
        "global_load_dwordx4 v[120:123], %[wp], off offset:1088\n"
        "global_load_dwordx4 v[124:127], %[wp], off offset:1104\n"
        "global_load_dwordx4 v[128:131], %[wp], off offset:1120\n"
        "global_load_dwordx4 v[132:135], %[wp], off offset:1136\n"
        "global_load_dwordx4 v[136:139], %[wp], off offset:2048\n"
        "global_load_dwordx4 v[140:143], %[wp], off offset:2064\n"
        "global_load_dwordx4 v[144:147], %[wp], off offset:2080\n"
        "global_load_dwordx4 v[148:151], %[wp], off offset:2096\n"
        "global_load_dwordx4 v[152:155], %[wp], off offset:2112\n"
        "global_load_dwordx4 v[156:159], %[wp], off offset:2128\n"
        "global_load_dwordx4 v[160:163], %[wp], off offset:2144\n"
        "global_load_dwordx4 v[164:167], %[wp], off offset:2160\n"
        "global_load_dwordx4 v[168:171], %[wp], off offset:3072\n"
        "global_load_dwordx4 v[172:175], %[wp], off offset:3088\n"
        "global_load_dwordx4 v[176:179], %[wp], off offset:3104\n"
        "global_load_dwordx4 v[180:183], %[wp], off offset:3120\n"
        "global_load_dwordx4 v[184:187], %[wp], off offset:3136\n"
        "global_load_dwordx4 v[188:191], %[wp], off offset:3152\n"
        "global_load_dwordx4 v[192:195], %[wp], off offset:3168\n"
        "global_load_dwordx4 v[196:199], %[wp], off offset:3184\n"
        "v_mov_b32 v16, %[hvr]\n"
        "v_mov_b32 v17, %[hvw]\n"
        "v_mov_b32 v18, %[vio]\n"
        "s_movk_i32 s82, 0x200\n"
        "s_waitcnt vmcnt(0)\n"
        "LTOP_%=:\n"
        // ---- xi prefetch (all lanes; 8x dup; consumed after butterfly) ----
        "global_load_dwordx4 v[20:23], v18, %[iob]\n"
        // ---- hv: 8 broadcast b128, padded stride -> conflict-free ----
        "ds_read_b128 v[40:43], v16\n"
        "ds_read_b128 v[44:47], v16 offset:16\n"
        "ds_read_b128 v[48:51], v16 offset:32\n"
        "ds_read_b128 v[52:55], v16 offset:48\n"
        "ds_read_b128 v[56:59], v16 offset:64\n"
        "ds_read_b128 v[60:63], v16 offset:80\n"
        "ds_read_b128 v[64:67], v16 offset:96\n"
        "ds_read_b128 v[68:71], v16 offset:112\n"
        // ---- FMA m=0..3 (quads 0-3) ----
        "s_waitcnt lgkmcnt(4)\n"
        "v_pk_mul_f32 v[32:33], v[72:73],   v[40:41]\n"
        "v_pk_mul_f32 v[34:35], v[104:105], v[40:41]\n"
        "v_pk_mul_f32 v[36:37], v[136:137], v[40:41]\n"
        "v_pk_mul_f32 v[38:39], v[168:169], v[40:41]\n"
        "v_pk_fma_f32 v[32:33], v[74:75],   v[42:43], v[32:33]\n"
        "v_pk_fma_f32 v[34:35], v[106:107], v[42:43], v[34:35]\n"
        "v_pk_fma_f32 v[36:37], v[138:139], v[42:43], v[36:37]\n"
        "v_pk_fma_f32 v[38:39], v[170:171], v[42:43], v[38:39]\n"
        "v_pk_fma_f32 v[32:33], v[76:77],   v[44:45], v[32:33]\n"
        "v_pk_fma_f32 v[34:35], v[108:109], v[44:45], v[34:35]\n"
        "v_pk_fma_f32 v[36:37], v[140:141], v[44:45], v[36:37]\n"
        "v_pk_fma_f32 v[38:39], v[172:173], v[44:45], v[38:39]\n"
        "v_pk_fma_f32 v[32:33], v[78:79],   v[46:47], v[32:33]\n"
        "v_pk_fma_f32 v[34:35], v[110:111], v[46:47], v[34:35]\n"
        "v_pk_fma_f32 v[36:37], v[142:143], v[46:47], v[36:37]\n"
        "v_pk_fma_f32 v[38:39], v[174:175], v[46:47], v[38:39]\n"
        "v_pk_fma_f32 v[32:33], v[80:81],   v[48:49], v[32:33]\n"
        "v_pk_fma_f32 v[34:35], v[112:113], v[48:49], v[34:35]\n"
        "v_pk_fma_f32 v[36:37], v[144:145], v[48:49], v[36:37]\n"
        "v_pk_fma_f32 v[38:39], v[176:177], v[48:49], v[38:39]\n"
        "v_pk_fma_f32 v[32:33], v[82:83],   v[50:51], v[32:33]\n"
        "v_pk_fma_f32 v[34:35], v[114:115], v[50:51], v[34:35]\n"
        "v_pk_fma_f32 v[36:37], v[146:147], v[50:51], v[36:37]\n"
        "v_pk_fma_f32 v[38:39], v[178:179], v[50:51], v[38:39]\n"
        "v_pk_fma_f32 v[32:33], v[84:85],   v[52:53], v[32:33]\n"
        "v_pk_fma_f32 v[34:35], v[116:117], v[52:53], v[34:35]\n"
        "v_pk_fma_f32 v[36:37], v[148:149], v[52:53], v[36:37]\n"
        "v_pk_fma_f32 v[38:39], v[180:181], v[52:53], v[38:39]\n"
        "v_pk_fma_f32 v[32:33], v[86:87],   v[54:55], v[32:33]\n"
        "v_pk_fma_f32 v[34:35], v[118:119], v[54:55], v[34:35]\n"
        "v_pk_fma_f32 v[36:37], v[150:151], v[54:55], v[36:37]\n"
        "v_pk_fma_f32 v[38:39], v[182:183], v[54:55], v[38:39]\n"
        // ---- FMA m=4..7 (quads 4-7) ----
        "s_waitcnt lgkmcnt(0)\n"
        "v_pk_fma_f32 v[32:33], v[88:89],   v[56:57], v[32:33]\n"
        "v_pk_fma_f32 v[34:35], v[120:121], v[56:57], v[34:35]\n"
        "v_pk_fma_f32 v[36:37], v[152:153], v[56:57], v[36:37]\n"
        "v_pk_fma_f32 v[38:39], v[184:185], v[56:57], v[38:39]\n"
        "v_pk_fma_f32 v[32:33], v[90:91],   v[58:59], v[32:33]\n"
        "v_pk_fma_f32 v[34:35], v[122:123], v[58:59], v[34:35]\n"
        "v_pk_fma_f32 v[36:37], v[154:155], v[58:59], v[36:37]\n"
        "v_pk_fma_f32 v[38:39], v[186:187], v[58:59], v[38:39]\n"
        "v_pk_fma_f32 v[32:33], v[92:93],   v[60:61], v[32:33]\n"
        "v_pk_fma_f32 v[34:35], v[124:125], v[60:61], v[34:35]\n"
        "v_pk_fma_f32 v[36:37], v[156:157], v[60:61], v[36:37]\n"
        "v_pk_fma_f32 v[38:39], v[188:189], v[60:61], v[38:39]\n"
        "v_pk_fma_f32 v[32:33], v[94:95],   v[62:63], v[32:33]\n"
        "v_pk_fma_f32 v[34:35], v[126:127], v[62:63], v[34:35]\n"
        "v_pk_fma_f32 v[36:37], v[158:159], v[62:63], v[36:37]\n"
        "v_pk_fma_f32 v[38:39], v[190:191], v[62:63], v[38:39]\n"
        "v_pk_fma_f32 v[32:33], v[96:97],   v[64:65], v[32:33]\n"
        "v_pk_fma_f32 v[34:35], v[128:129], v[64:65], v[34:35]\n"
        "v_pk_fma_f32 v[36:37], v[160:161], v[64:65], v[36:37]\n"
        "v_pk_fma_f32 v[38:39], v[192:193], v[64:65], v[38:39]\n"
        "v_pk_fma_f32 v[32:33], v[98:99],   v[66:67], v[32:33]\n"
        "v_pk_fma_f32 v[34:35], v[130:131], v[66:67], v[34:35]\n"
        "v_pk_fma_f32 v[36:37], v[162:163], v[66:67], v[36:37]\n"
        "v_pk_fma_f32 v[38:39], v[194:195], v[66:67], v[38:39]\n"
        "v_pk_fma_f32 v[32:33], v[100:101], v[68:69], v[32:33]\n"
        "v_pk_fma_f32 v[34:35], v[132:133], v[68:69], v[34:35]\n"
        "v_pk_fma_f32 v[36:37], v[164:165], v[68:69], v[36:37]\n"
        "v_pk_fma_f32 v[38:39], v[196:197], v[68:69], v[38:39]\n"
        "v_pk_fma_f32 v[32:33], v[102:103], v[70:71], v[32:33]\n"
        "v_pk_fma_f32 v[34:35], v[134:135], v[70:71], v[34:35]\n"
        "v_pk_fma_f32 v[36:37], v[166:167], v[70:71], v[36:37]\n"
        "v_pk_fma_f32 v[38:39], v[198:199], v[70:71], v[38:39]\n"
        // ---- merge pk pairs -> 4 col partials ----
        "v_add_f32 v26, v32, v33\n"
        "v_add_f32 v27, v34, v35\n"
        "v_add_f32 v28, v36, v37\n"
        "v_add_f32 v29, v38, v39\n"
        // ---- butterfly over kg: xor1, xor2 (quad_perm), xor8 (row_ror:8) ----
        "v_add_f32 v26, v26, v26 quad_perm:[1,0,3,2] row_mask:0xf bank_mask:0xf\n"
        "v_add_f32 v27, v27, v27 quad_perm:[1,0,3,2] row_mask:0xf bank_mask:0xf\n"
        "v_add_f32 v28, v28, v28 quad_perm:[1,0,3,2] row_mask:0xf bank_mask:0xf\n"
        "v_add_f32 v29, v29, v29 quad_perm:[1,0,3,2] row_mask:0xf bank_mask:0xf\n"
        "v_add_f32 v26, v26, v26 quad_perm:[2,3,0,1] row_mask:0xf bank_mask:0xf\n"
        "v_add_f32 v27, v27, v27 quad_perm:[2,3,0,1] row_mask:0xf bank_mask:0xf\n"
        "v_add_f32 v28, v28, v28 quad_perm:[2,3,0,1] row_mask:0xf bank_mask:0xf\n"
        "v_add_f32 v29, v29, v29 quad_perm:[2,3,0,1] row_mask:0xf bank_mask:0xf\n"
        "v_add_f32 v26, v26, v26 row_ror:8 row_mask:0xf bank_mask:0xf\n"
        "v_add_f32 v27, v27, v27 row_ror:8 row_mask:0xf bank_mask:0xf\n"
        "v_add_f32 v28, v28, v28 row_ror:8 row_mask:0xf bank_mask:0xf\n"
        "v_add_f32 v29, v29, v29 row_ror:8 row_mask:0xf bank_mask:0xf\n"
        // ---- + xi (drains prev store too), tanh x4 ----
        "s_waitcnt vmcnt(0)\n"
        "v_add_f32 v20, v20, v26\n"
        "v_add_f32 v21, v21, v27\n"
        "v_add_f32 v22, v22, v28\n"
        "v_add_f32 v23, v23, v29\n"
        "v_mul_f32 v20, 0x4038aa3b, v20\n"
        "v_mul_f32 v21, 0x4038aa3b, v21\n"
        "v_mul_f32 v22, 0x4038aa3b, v22\n"
        "v_mul_f32 v23, 0x4038aa3b, v23\n"
        "v_exp_f32 v20, v20\n"
        "v_exp_f32 v21, v21\n"
        "v_exp_f32 v22, v22\n"
        "v_exp_f32 v23, v23\n"
        "v_add_f32 v20, 1.0, v20\n"
        "v_add_f32 v21, 1.0, v21\n"
        "v_add_f32 v22, 1.0, v22\n"
        "v_add_f32 v23, 1.0, v23\n"
        "v_rcp_f32 v20, v20\n"
        "v_rcp_f32 v21, v21\n"
        "v_rcp_f32 v22, v22\n"
        "v_rcp_f32 v23, v23\n"
        "v_fma_f32 v20, -2.0, v20, 1.0\n"
        "v_fma_f32 v21, -2.0, v21, 1.0\n"
        "v_fma_f32 v22, -2.0, v22, 1.0\n"
        "v_fma_f32 v23, -2.0, v23, 1.0\n"
        // ---- masked stores: LDS next-buffer + global h ----
        "s_and_saveexec_b64 s[84:85], %[msk]\n"
        "ds_write_b128 v17, v[20:23]\n"
        "global_store_dwordx4 v18, v[20:23], %[iob]\n"
        "s_mov_b64 exec, s[84:85]\n"
        // ---- advance, barrier, toggle ----
        "v_add_u32 v18, 0x40000, v18\n"
        "s_waitcnt lgkmcnt(0)\n"
        "s_barrier\n"
        "v_xor_b32 v16, 0x800, v16\n"
        "v_xor_b32 v17, 0x800, v17\n"
        "s_sub_u32 s82, s82, 1\n"
        "s_cmp_lg_u32 s82, 0\n"
        "s_cbranch_scc1 LTOP_%=\n"
        :
        : [wp] "v"(wp), [iob] "s"(iob), [msk] "s"(msk),
          [hvr] "v"(hvr), [hvw] "v"(hvw), [vio] "v"(vio)
        : "memory", "scc", "s82", "s84", "s85",
          "v16","v17","v18","v19","v20","v21","v22","v23",
          "v24","v25","v26","v27","v28","v29","v30","v31",
          "v32","v33","v34","v35","v36","v37","v38","v39",
          "v40","v41","v42","v43","v44","v45","v46","v47",
          "v48","v49","v50","v51","v52","v53","v54","v55",
          "v56","v57","v58","v59","v60","v61","v62","v63",
          "v64","v65","v66","v67","v68","v69","v70","v71",
          "v72","v73","v74","v75","v76","v77","v78","v79",
          "v80","v81","v82","v83","v84","v85","v86","v87",
          "v88","v89","v90","v91","v92","v93","v94","v95",
          "v96","v97","v98","v99","v100","v101","v102","v103",
          "v104","v105","v106","v107","v108","v109","v110","v111",
          "v112","v113","v114","v115","v116","v117","v118","v119",
          "v120","v121","v122","v123","v124","v125","v126","v127",
          "v128","v129","v130","v131","v132","v133","v134","v135",
          "v136","v137","v138","v139","v140","v141","v142","v143",
          "v144","v145","v146","v147","v148","v149","v150","v151",
          "v152","v153","v154","v155","v156","v157","v158","v159",
          "v160","v161","v162","v163","v164","v165","v166","v167",
          "v168","v169","v170","v171","v172","v173","v174","v175",
          "v176","v177","v178","v179","v180","v181","v182","v183",
          "v184","v185","v186","v187","v188","v189","v190","v191",
          "v192","v193","v194","v195","v196","v197","v198","v199");
}

extern "C" void kernel_launch(void* const* d_in, const int* in_sizes, int n_in,
                              void* d_out, int out_size, void* d_ws, size_t ws_size,
                              hipStream_t stream) {
    const float* x  = (const float*)d_in[0];  // [T,B,I]
    const float* h0 = (const float*)d_in[1];  // [B,H]
    const float* Wi = (const float*)d_in[2];  // [H,I]
    const float* Wh = (const float*)d_in[3];  // [H,H]
    const float* bh = (const float*)d_in[4];  // [H]
    float* out = (float*)d_out;               // [T,B,H]

    dim3 pgrid(TT * BB / 64, HH / 64);
    proj_kernel<<<pgrid, 256, 0, stream>>>(x, Wi, bh, out);
    rec_kernel<<<BB, 512, 0, stream>>>(Wh, h0, out);
}

// Round 9
// 400.596 us; speedup vs baseline: 1.2024x; 1.0862x over previous
//
#include <hip/hip_runtime.h>
#include <hip/hip_bf16.h>
#include <math.h>

// Problem dims (fixed): T=512, B=256, I=128, H=256
#define TT 512
#define BB 256
#define II 128
#define HH 256

// ---------------------------------------------------------------------------
// Kernel 1: input projection  xi[m][n] = sum_k x[m][k]*Wi[n][k] + bh[n]
// ---------------------------------------------------------------------------
__global__ __launch_bounds__(256) void proj_kernel(
    const float* __restrict__ x, const float* __restrict__ Wi,
    const float* __restrict__ bh, float* __restrict__ out)
{
    __shared__ float xt[128][68];
    __shared__ float wt[128][64];

    const int tid = threadIdx.x;
    const int m0 = blockIdx.x * 64;
    const int j0 = blockIdx.y * 64;

    {
        const int r  = tid & 63;
        const int kc = tid >> 6;
        const float* xsrc = x  + (size_t)(m0 + r) * II + kc * 32;
        const float* wsrc = Wi + (size_t)(j0 + r) * II + kc * 32;
#pragma unroll
        for (int u = 0; u < 8; ++u) {
            float4 v = *(const float4*)(xsrc + u * 4);
            int k = kc * 32 + u * 4;
            xt[k + 0][r] = v.x; xt[k + 1][r] = v.y;
            xt[k + 2][r] = v.z; xt[k + 3][r] = v.w;
        }
#pragma unroll
        for (int u = 0; u < 8; ++u) {
            float4 v = *(const float4*)(wsrc + u * 4);
            int k = kc * 32 + u * 4;
            wt[k + 0][r] = v.x; wt[k + 1][r] = v.y;
            wt[k + 2][r] = v.z; wt[k + 3][r] = v.w;
        }
    }
    __syncthreads();

    const int ty = tid >> 4, tx = tid & 15;
    const int r0 = ty * 4, c0 = tx * 4;
    float acc[4][4] = {};
#pragma unroll 4
    for (int k = 0; k < 128; ++k) {
        float4 a = *(const float4*)&xt[k][r0];
        float4 b = *(const float4*)&wt[k][c0];
        float av[4] = {a.x, a.y, a.z, a.w};
        float bv[4] = {b.x, b.y, b.z, b.w};
#pragma unroll
        for (int i = 0; i < 4; ++i)
#pragma unroll
            for (int j = 0; j < 4; ++j)
                acc[i][j] += av[i] * bv[j];
    }

    float4 bias = *(const float4*)(bh + j0 + c0);
    float bvv[4] = {bias.x, bias.y, bias.z, bias.w};
#pragma unroll
    for (int i = 0; i < 4; ++i) {
        float4 o;
        o.x = acc[i][0] + bvv[0];
        o.y = acc[i][1] + bvv[1];
        o.z = acc[i][2] + bvv[2];
        o.w = acc[i][3] + bvv[3];
        *(float4*)(out + (size_t)(m0 + r0 + i) * HH + j0 + c0) = o;
    }
}

// ---------------------------------------------------------------------------
// Kernel 2: recurrence (r8 skeleton + distributed tanh + xi prefetch-ahead +
// per-quad lgkm waits). 512 threads = 8 waves, 1 block per batch row.
//   Wave q owns cols [32q,+32). Lane: kg=(l&3)|((l>>1)&4) (8 k-groups of 32),
//   cg=((l>>2)&1)|((l>>3)&6) (8 col-quads). Wh frag 4col x 32k in v72-v199.
//   h in LDS, kg-group padded to 144B, double-buffered (+0x800), 1 barrier.
//   Butterfly xor1/xor2/xor8 (quad_perm, row_ror:8) -> all lanes hold all 4
//   col sums; 3 cndmask select ONE col (by kg&3), 1 xi add, 1 tanh chain
//   (was 4 -> cuts ~110 VALU cyc/wave/step). kg<4 lanes write real cols;
//   kg>=4 lanes write LDS padding slots (0xD00^0x800-toggled, conflict-free)
//   and duplicate global addrs (coalescer merges) -> no exec masking.
//   xi prefetched ONE STEP AHEAD (2-body unroll, v20/v21; vmcnt(2) =
//   issue-order counted wait; v_min_u32 clamps the final OOB prefetch).
// ---------------------------------------------------------------------------

#define RNN_CHUNK(CNT, A0,A1,B0,B1,C0,C1,D0,D1, H0,H1) \
        "s_waitcnt lgkmcnt(" CNT ")\n" \
        "v_pk_fma_f32 v[32:33], v[" A0 "], v[" H0 "], v[32:33]\n" \
        "v_pk_fma_f32 v[34:35], v[" B0 "], v[" H0 "], v[34:35]\n" \
        "v_pk_fma_f32 v[36:37], v[" C0 "], v[" H0 "], v[36:37]\n" \
        "v_pk_fma_f32 v[38:39], v[" D0 "], v[" H0 "], v[38:39]\n" \
        "v_pk_fma_f32 v[32:33], v[" A1 "], v[" H1 "], v[32:33]\n" \
        "v_pk_fma_f32 v[34:35], v[" B1 "], v[" H1 "], v[34:35]\n" \
        "v_pk_fma_f32 v[36:37], v[" C1 "], v[" H1 "], v[36:37]\n" \
        "v_pk_fma_f32 v[38:39], v[" D1 "], v[" H1 "], v[38:39]\n"

#define RNN_BODY(XN, XC) \
        /* hv: 8 broadcast b128 (padded, conflict-free) */ \
        "ds_read_b128 v[40:43], v16\n" \
        "ds_read_b128 v[44:47], v16 offset:16\n" \
        "ds_read_b128 v[48:51], v16 offset:32\n" \
        "ds_read_b128 v[52:55], v16 offset:48\n" \
        "ds_read_b128 v[56:59], v16 offset:64\n" \
        "ds_read_b128 v[60:63], v16 offset:80\n" \
        "ds_read_b128 v[64:67], v16 offset:96\n" \
        "ds_read_b128 v[68:71], v16 offset:112\n" \
        /* xi prefetch for NEXT step; clamp final OOB plane */ \
        "global_load_dword " XN ", v18, %[iob]\n" \
        "v_add_u32 v18, 0x40000, v18\n" \
        "v_min_u32 v18, %[viomax], v18\n" \
        /* chunk 0 (quad 0): pk_mul init */ \
        "s_waitcnt lgkmcnt(7)\n" \
        "v_pk_mul_f32 v[32:33], v[72:73],   v[40:41]\n" \
        "v_pk_mul_f32 v[34:35], v[104:105], v[40:41]\n" \
        "v_pk_mul_f32 v[36:37], v[136:137], v[40:41]\n" \
        "v_pk_mul_f32 v[38:39], v[168:169], v[40:41]\n" \
        "v_pk_fma_f32 v[32:33], v[74:75],   v[42:43], v[32:33]\n" \
        "v_pk_fma_f32 v[34:35], v[106:107], v[42:43], v[34:35]\n" \
        "v_pk_fma_f32 v[36:37], v[138:139], v[42:43], v[36:37]\n" \
        "v_pk_fma_f32 v[38:39], v[170:171], v[42:43], v[38:39]\n" \
        RNN_CHUNK("6","76:77","78:79","108:109","110:111","140:141","142:143","172:173","174:175","44:45","46:47") \
        RNN_CHUNK("5","80:81","82:83","112:113","114:115","144:145","146:147","176:177","178:179","48:49","50:51") \
        RNN_CHUNK("4","84:85","86:87","116:117","118:119","148:149","150:151","180:181","182:183","52:53","54:55") \
        RNN_CHUNK("3","88:89","90:91","120:121","122:123","152:153","154:155","184:185","186:187","56:57","58:59") \
        RNN_CHUNK("2","92:93","94:95","124:125","126:127","156:157","158:159","188:189","190:191","60:61","62:63") \
        RNN_CHUNK("1","96:97","98:99","128:129","130:131","160:161","162:163","192:193","194:195","64:65","66:67") \
        RNN_CHUNK("0","100:101","102:103","132:133","134:135","164:165","166:167","196:197","198:199","68:69","70:71") \
        /* merge pk pairs -> 4 col sums */ \
        "v_add_f32 v26, v32, v33\n" \
        "v_add_f32 v27, v34, v35\n" \
        "v_add_f32 v28, v36, v37\n" \
        "v_add_f32 v29, v38, v39\n" \
        /* butterfly over kg: xor1, xor2, xor8 */ \
        "v_add_f32 v26, v26, v26 quad_perm:[1,0,3,2] row_mask:0xf bank_mask:0xf\n" \
        "v_add_f32 v27, v27, v27 quad_perm:[1,0,3,2] row_mask:0xf bank_mask:0xf\n" \
        "v_add_f32 v28, v28, v28 quad_perm:[1,0,3,2] row_mask:0xf bank_mask:0xf\n" \
        "v_add_f32 v29, v29, v29 quad_perm:[1,0,3,2] row_mask:0xf bank_mask:0xf\n" \
        "v_add_f32 v26, v26, v26 quad_perm:[2,3,0,1] row_mask:0xf bank_mask:0xf\n" \
        "v_add_f32 v27, v27, v27 quad_perm:[2,3,0,1] row_mask:0xf bank_mask:0xf\n" \
        "v_add_f32 v28, v28, v28 quad_perm:[2,3,0,1] row_mask:0xf bank_mask:0xf\n" \
        "v_add_f32 v29, v29, v29 quad_perm:[2,3,0,1] row_mask:0xf bank_mask:0xf\n" \
        "v_add_f32 v26, v26, v26 row_ror:8 row_mask:0xf bank_mask:0xf\n" \
        "v_add_f32 v27, v27, v27 row_ror:8 row_mask:0xf bank_mask:0xf\n" \
        "v_add_f32 v28, v28, v28 row_ror:8 row_mask:0xf bank_mask:0xf\n" \
        "v_add_f32 v29, v29, v29 row_ror:8 row_mask:0xf bank_mask:0xf\n" \
        /* select this lane's column (kg&3) */ \
        "v_cndmask_b32 v30, v26, v27, %[m0]\n" \
        "v_cndmask_b32 v31, v28, v29, %[m0]\n" \
        "v_cndmask_b32 v30, v30, v31, %[m1]\n" \
        /* xi (prefetched last step; vmcnt(2) = all but 2 newest done) */ \
        "s_waitcnt vmcnt(2)\n" \
        "v_add_f32 v30, v30, " XC "\n" \
        /* tanh = 1 - 2/(exp2(x*2log2e)+1) */ \
        "v_mul_f32 v19, 0x4038aa3b, v30\n" \
        "v_exp_f32 v19, v19\n" \
        "s_nop 1\n" \
        "v_add_f32 v19, 1.0, v19\n" \
        "v_rcp_f32 v19, v19\n" \
        "s_nop 1\n" \
        "v_fma_f32 v30, -2.0, v19, 1.0\n" \
        /* stores: LDS next-buffer (kg>=4 -> padding slot) + global h */ \
        "ds_write_b32 v17, v30\n" \
        "global_store_dword v23, v30, %[iob]\n" \
        "v_add_u32 v23, 0x40000, v23\n" \
        "s_waitcnt lgkmcnt(0)\n" \
        "s_barrier\n" \
        "v_xor_b32 v16, 0x800, v16\n" \
        "v_xor_b32 v17, 0x800, v17\n"

__global__ __launch_bounds__(512, 2) void rec_kernel(
    const float* __restrict__ Wh, const float* __restrict__ h0,
    float* __restrict__ io)
{
    __shared__ float hbuf[864];  // buf0 [0,1152) buf1 [0x800,+1152) + pads

    const int tid  = threadIdx.x;
    const int b    = blockIdx.x;
    const int lane = tid & 63;
    const int q    = tid >> 6;                       // wave id 0..7
    const int kg   = (lane & 3) | ((lane >> 1) & 4); // 0..7
    const int cg   = ((lane >> 2) & 1) | ((lane >> 3) & 6); // 0..7
    const int col0 = 32 * q + 4 * cg;
    const int col  = col0 + (kg & 3);                // finalize column

    const float* wp  = Wh + (size_t)col0 * HH + kg * 32;
    const float* iob = io + (size_t)b * HH;
    unsigned hbase = (unsigned)(size_t)&hbuf[0];
    unsigned hvr = hbase + kg * 144;                 // read base (buf0)
    // write addr: real col slot (kg<4) or padding dummy (kg>=4)
    unsigned hvw = (kg < 4)
        ? hbase + 0x800 + q * 144 + (4 * cg + kg) * 4
        : hbase + 0xD00 + cg * 16 + (kg & 3) * 4;    // toggles 0xD00<->0x500
    unsigned vio = (unsigned)(col * 4);
    unsigned viomax = vio + 511u * 0x40000u;         // last valid xi plane
    unsigned long long m0 = __ballot((lane & 1) != 0);
    unsigned long long m1 = __ballot((lane & 2) != 0);

    if (tid < HH) hbuf[(tid >> 5) * 36 + (tid & 31)] = h0[(size_t)b * HH + tid];
    __syncthreads();

    asm volatile(
        // ---- Wh fragment: w[j][m] -> v[72+32j+4m] ----
        "global_load_dwordx4 v[72:75],   %[wp], off\n"
        "global_load_dwordx4 v[76:79],   %[wp], off offset:16\n"
        "global_load_dwordx4 v[80:83],   %[wp], off offset:32\n"
        "global_load_dwordx4 v[84:87],   %[wp], off offset:48\n"
        "global_load_dwordx4 v[88:91],   %[wp], off offset:64\n"
        "global_load_dwordx4 v[92:95],   %[wp], off offset:80\n"
        "global_load_dwordx4 v[96:99],   %[wp], off offset:96\n"
        "global_load_dwordx4 v[100:103], %[wp], off offset:112\n"
        "global_load_dwordx4 v[104:107], %[wp], off offset:1024\n"
        "global_load_dwordx4 v[108:111], %[wp], off offset:1040\n"
        "global_load_dwordx4 v[112:115], %[wp], off offset:1056\n"
        "global_load_dwordx4 v[116:119], %[wp], off offset:1072\n"
        "global_load_dwordx4 v[120:123], %[wp], off offset:1088\n"
        "global_load_dwordx4 v[124:127], %[wp], off offset:1104\n"
        "global_load_dwordx4 v[128:131], %[wp], off offset:1120\n"
        "global_load_dwordx4 v[132:135], %[wp], off offset:1136\n"
        "global_load_dwordx4 v[136:139], %[wp], off offset:2048\n"
        "global_load_dwordx4 v[140:143], %[wp], off offset:2064\n"
        "global_load_dwordx4 v[144:147], %[wp], off offset:2080\n"
        "global_load_dwordx4 v[148:151], %[wp], off offset:2096\n"
        "global_load_dwordx4 v[152:155], %[wp], off offset:2112\n"
        "global_load_dwordx4 v[156:159], %[wp], off offset:2128\n"
        "global_load_dwordx4 v[160:163], %[wp], off offset:2144\n"
        "global_load_dwordx4 v[164:167], %[wp], off offset:2160\n"
        "global_load_dwordx4 v[168:171], %[wp], off offset:3072\n"
        "global_load_dwordx4 v[172:175], %[wp], off offset:3088\n"
        "global_load_dwordx4 v[176:179], %[wp], off offset:3104\n"
        "global_load_dwordx4 v[180:183], %[wp], off offset:3120\n"
        "global_load_dwordx4 v[184:187], %[wp], off offset:3136\n"
        "global_load_dwordx4 v[188:191], %[wp], off offset:3152\n"
        "global_load_dwordx4 v[192:195], %[wp], off offset:3168\n"
        "global_load_dwordx4 v[196:199], %[wp], off offset:3184\n"
        // ---- init + xi_0 prologue load ----
        "v_mov_b32 v16, %[hvr]\n"
        "v_mov_b32 v17, %[hvw]\n"
        "v_mov_b32 v18, %[vio]\n"
        "v_mov_b32 v23, %[vio]\n"
        "global_load_dword v21, v18, %[iob]\n"
        "v_add_u32 v18, 0x40000, v18\n"
        "s_movk_i32 s82, 0x100\n"
        "s_waitcnt vmcnt(0)\n"
        "LTOP_%=:\n"
        RNN_BODY("v20", "v21")
        RNN_BODY("v21", "v20")
        "s_sub_u32 s82, s82, 1\n"
        "s_cmp_lg_u32 s82, 0\n"
        "s_cbranch_scc1 LTOP_%=\n"
        :
        : [wp] "v"(wp), [iob] "s"(iob),
          [hvr] "v"(hvr), [hvw] "v"(hvw), [vio] "v"(vio),
          [viomax] "v"(viomax), [m0] "s"(m0), [m1] "s"(m1)
        : "memory", "scc", "s82",
          "v16","v17","v18","v19","v20","v21","v22","v23",
          "v24","v25","v26","v27","v28","v29","v30","v31",
          "v32","v33","v34","v35","v36","v37","v38","v39",
          "v40","v41","v42","v43","v44","v45","v46","v47",
          "v48","v49","v50","v51","v52","v53","v54","v55",
          "v56","v57","v58","v59","v60","v61","v62","v63",
          "v64","v65","v66","v67","v68","v69","v70","v71",
          "v72","v73","v74","v75","v76","v77","v78","v79",
          "v80","v81","v82","v83","v84","v85","v86","v87",
          "v88","v89","v90","v91","v92","v93","v94","v95",
          "v96","v97","v98","v99","v100","v101","v102","v103",
          "v104","v105","v106","v107","v108","v109","v110","v111",
          "v112","v113","v114","v115","v116","v117","v118","v119",
          "v120","v121","v122","v123","v124","v125","v126","v127",
          "v128","v129","v130","v131","v132","v133","v134","v135",
          "v136","v137","v138","v139","v140","v141","v142","v143",
          "v144","v145","v146","v147","v148","v149","v150","v151",
          "v152","v153","v154","v155","v156","v157","v158","v159",
          "v160","v161","v162","v163","v164","v165","v166","v167",
          "v168","v169","v170","v171","v172","v173","v174","v175",
          "v176","v177","v178","v179","v180","v181","v182","v183",
          "v184","v185","v186","v187","v188","v189","v190","v191",
          "v192","v193","v194","v195","v196","v197","v198","v199");
}

extern "C" void kernel_launch(void* const* d_in, const int* in_sizes, int n_in,
                              void* d_out, int out_size, void* d_ws, size_t ws_size,
                              hipStream_t stream) {
    const float* x  = (const float*)d_in[0];  // [T,B,I]
    const float* h0 = (const float*)d_in[1];  // [B,H]
    const float* Wi = (const float*)d_in[2];  // [H,I]
    const float* Wh = (const float*)d_in[3];  // [H,H]
    const float* bh = (const float*)d_in[4];  // [H]
    float* out = (float*)d_out;               // [T,B,H]

    dim3 pgrid(TT * BB / 64, HH / 64);
    proj_kernel<<<pgrid, 256, 0, stream>>>(x, Wi, bh, out);
    rec_kernel<<<BB, 512, 0, stream>>>(Wh, h0, out);
}

// Round 10
// 397.446 us; speedup vs baseline: 1.2119x; 1.0079x over previous
//
#include <hip/hip_runtime.h>
#include <hip/hip_bf16.h>
#include <math.h>

// Problem dims (fixed): T=512, B=256, I=128, H=256
#define TT 512
#define BB 256
#define II 128
#define HH 256

// 2*log2(e): Wh and xi are pre-scaled by this so the recurrence tanh is
// exp2-direct (saves one v_mul on the per-step critical path).
#define TANH_S 2.885390043258667f

// ---------------------------------------------------------------------------
// Kernel 1: input projection  xi[m][n] = (sum_k x[m][k]*Wi[n][k] + bh[n]) * S
//   M = T*B = 131072, K = 128, N = 256. Written into d_out (later overwritten
//   in-place by the recurrence with h_t).  K-loop chunked by 8 with all 16
//   ds_read_b128 issued up-front per chunk (r9's unroll-4 version stalled on
//   ds latency every 4 k -> ~103us vs ~45us roofline).
// ---------------------------------------------------------------------------
__global__ __launch_bounds__(256) void proj_kernel(
    const float* __restrict__ x, const float* __restrict__ Wi,
    const float* __restrict__ bh, float* __restrict__ out)
{
    __shared__ float xt[128][68];
    __shared__ float wt[128][64];

    const int tid = threadIdx.x;
    const int m0 = blockIdx.x * 64;
    const int j0 = blockIdx.y * 64;

    {
        const int r  = tid & 63;
        const int kc = tid >> 6;
        const float* xsrc = x  + (size_t)(m0 + r) * II + kc * 32;
        const float* wsrc = Wi + (size_t)(j0 + r) * II + kc * 32;
#pragma unroll
        for (int u = 0; u < 8; ++u) {
            float4 v = *(const float4*)(xsrc + u * 4);
            int k = kc * 32 + u * 4;
            xt[k + 0][r] = v.x; xt[k + 1][r] = v.y;
            xt[k + 2][r] = v.z; xt[k + 3][r] = v.w;
        }
#pragma unroll
        for (int u = 0; u < 8; ++u) {
            float4 v = *(const float4*)(wsrc + u * 4);
            int k = kc * 32 + u * 4;
            wt[k + 0][r] = v.x; wt[k + 1][r] = v.y;
            wt[k + 2][r] = v.z; wt[k + 3][r] = v.w;
        }
    }
    __syncthreads();

    const int ty = tid >> 4, tx = tid & 15;
    const float* xp = &xt[0][ty * 4];
    const float* wp = &wt[0][tx * 4];
    float acc[4][4] = {};

#pragma unroll
    for (int kk = 0; kk < 128; kk += 8) {
        float4 av[8], bv[8];
#pragma unroll
        for (int u = 0; u < 8; ++u) {
            av[u] = *(const float4*)(xp + (size_t)(kk + u) * 68);
            bv[u] = *(const float4*)(wp + (size_t)(kk + u) * 64);
        }
#pragma unroll
        for (int u = 0; u < 8; ++u) {
            float a4[4] = {av[u].x, av[u].y, av[u].z, av[u].w};
            float b4[4] = {bv[u].x, bv[u].y, bv[u].z, bv[u].w};
#pragma unroll
            for (int i = 0; i < 4; ++i)
#pragma unroll
                for (int j = 0; j < 4; ++j)
                    acc[i][j] += a4[i] * b4[j];
        }
    }

    float4 bias = *(const float4*)(bh + j0 + tx * 4);
    float bvv[4] = {bias.x, bias.y, bias.z, bias.w};
#pragma unroll
    for (int i = 0; i < 4; ++i) {
        float4 o;
        o.x = (acc[i][0] + bvv[0]) * TANH_S;
        o.y = (acc[i][1] + bvv[1]) * TANH_S;
        o.z = (acc[i][2] + bvv[2]) * TANH_S;
        o.w = (acc[i][3] + bvv[3]) * TANH_S;
        *(float4*)(out + (size_t)(m0 + ty * 4 + i) * HH + j0 + tx * 4) = o;
    }
}

// ---------------------------------------------------------------------------
// Kernel 2: recurrence (r9 skeleton + pre-scaled Wh/xi + exec-masked ds_write
// + nop/bookkeeping trims). 512 threads = 8 waves, 1 block per batch row.
//   Wave q owns cols [32q,+32). Lane: kg=(l&3)|((l>>1)&4), cg from bits 2,4,5.
//   Wh frag (4col x 32k, PRE-SCALED by 2log2e) in v72-v199 (asm-pinned).
//   h LDS: kg-group padded to 144B, double-buffered (+0x800), 1 barrier/step.
//   Butterfly xor1/xor2/xor8 (DPP) -> select 1 col (cndmask x3) -> +xi
//   (pre-scaled) -> tanh = 1 - 2*rcp(exp2(arg)+1).
//   ds_write exec-masked to kg<4 lanes (r9's all-lane dummy writes cost 1.8M
//   bank-conflict cycles); global store unmasked (dup addrs merge).
//   xi prefetched one step ahead (vmcnt(2) counted wait).
// ---------------------------------------------------------------------------

#define RNN_CHUNK(CNT, A0,A1,B0,B1,C0,C1,D0,D1, H0,H1) \
        "s_waitcnt lgkmcnt(" CNT ")\n" \
        "v_pk_fma_f32 v[32:33], v[" A0 "], v[" H0 "], v[32:33]\n" \
        "v_pk_fma_f32 v[34:35], v[" B0 "], v[" H0 "], v[34:35]\n" \
        "v_pk_fma_f32 v[36:37], v[" C0 "], v[" H0 "], v[36:37]\n" \
        "v_pk_fma_f32 v[38:39], v[" D0 "], v[" H0 "], v[38:39]\n" \
        "v_pk_fma_f32 v[32:33], v[" A1 "], v[" H1 "], v[32:33]\n" \
        "v_pk_fma_f32 v[34:35], v[" B1 "], v[" H1 "], v[34:35]\n" \
        "v_pk_fma_f32 v[36:37], v[" C1 "], v[" H1 "], v[36:37]\n" \
        "v_pk_fma_f32 v[38:39], v[" D1 "], v[" H1 "], v[38:39]\n"

#define RNN_BODY(XN, XC) \
        /* hv: 8 broadcast b128 (padded, conflict-free) */ \
        "ds_read_b128 v[40:43], v16\n" \
        "ds_read_b128 v[44:47], v16 offset:16\n" \
        "ds_read_b128 v[48:51], v16 offset:32\n" \
        "ds_read_b128 v[52:55], v16 offset:48\n" \
        "ds_read_b128 v[56:59], v16 offset:64\n" \
        "ds_read_b128 v[60:63], v16 offset:80\n" \
        "ds_read_b128 v[64:67], v16 offset:96\n" \
        "ds_read_b128 v[68:71], v16 offset:112\n" \
        /* shadow work while first read lands */ \
        "v_xor_b32 v16, 0x800, v16\n" \
        "global_load_dword " XN ", v18, %[iob]\n" \
        "v_add_u32 v18, 0x40000, v18\n" \
        "v_min_u32 v18, %[viomax], v18\n" \
        /* chunk 0 (quad 0): pk_mul init */ \
        "s_waitcnt lgkmcnt(7)\n" \
        "v_pk_mul_f32 v[32:33], v[72:73],   v[40:41]\n" \
        "v_pk_mul_f32 v[34:35], v[104:105], v[40:41]\n" \
        "v_pk_mul_f32 v[36:37], v[136:137], v[40:41]\n" \
        "v_pk_mul_f32 v[38:39], v[168:169], v[40:41]\n" \
        "v_pk_fma_f32 v[32:33], v[74:75],   v[42:43], v[32:33]\n" \
        "v_pk_fma_f32 v[34:35], v[106:107], v[42:43], v[34:35]\n" \
        "v_pk_fma_f32 v[36:37], v[138:139], v[42:43], v[36:37]\n" \
        "v_pk_fma_f32 v[38:39], v[170:171], v[42:43], v[38:39]\n" \
        RNN_CHUNK("6","76:77","78:79","108:109","110:111","140:141","142:143","172:173","174:175","44:45","46:47") \
        RNN_CHUNK("5","80:81","82:83","112:113","114:115","144:145","146:147","176:177","178:179","48:49","50:51") \
        RNN_CHUNK("4","84:85","86:87","116:117","118:119","148:149","150:151","180:181","182:183","52:53","54:55") \
        RNN_CHUNK("3","88:89","90:91","120:121","122:123","152:153","154:155","184:185","186:187","56:57","58:59") \
        RNN_CHUNK("2","92:93","94:95","124:125","126:127","156:157","158:159","188:189","190:191","60:61","62:63") \
        RNN_CHUNK("1","96:97","98:99","128:129","130:131","160:161","162:163","192:193","194:195","64:65","66:67") \
        RNN_CHUNK("0","100:101","102:103","132:133","134:135","164:165","166:167","196:197","198:199","68:69","70:71") \
        /* merge pk pairs -> 4 col sums */ \
        "v_add_f32 v26, v32, v33\n" \
        "v_add_f32 v27, v34, v35\n" \
        "v_add_f32 v28, v36, v37\n" \
        "v_add_f32 v29, v38, v39\n" \
        /* butterfly over kg: xor1, xor2, xor8 */ \
        "v_add_f32 v26, v26, v26 quad_perm:[1,0,3,2] row_mask:0xf bank_mask:0xf\n" \
        "v_add_f32 v27, v27, v27 quad_perm:[1,0,3,2] row_mask:0xf bank_mask:0xf\n" \
        "v_add_f32 v28, v28, v28 quad_perm:[1,0,3,2] row_mask:0xf bank_mask:0xf\n" \
        "v_add_f32 v29, v29, v29 quad_perm:[1,0,3,2] row_mask:0xf bank_mask:0xf\n" \
        "v_add_f32 v26, v26, v26 quad_perm:[2,3,0,1] row_mask:0xf bank_mask:0xf\n" \
        "v_add_f32 v27, v27, v27 quad_perm:[2,3,0,1] row_mask:0xf bank_mask:0xf\n" \
        "v_add_f32 v28, v28, v28 quad_perm:[2,3,0,1] row_mask:0xf bank_mask:0xf\n" \
        "v_add_f32 v29, v29, v29 quad_perm:[2,3,0,1] row_mask:0xf bank_mask:0xf\n" \
        "v_add_f32 v26, v26, v26 row_ror:8 row_mask:0xf bank_mask:0xf\n" \
        "v_add_f32 v27, v27, v27 row_ror:8 row_mask:0xf bank_mask:0xf\n" \
        "v_add_f32 v28, v28, v28 row_ror:8 row_mask:0xf bank_mask:0xf\n" \
        "v_add_f32 v29, v29, v29 row_ror:8 row_mask:0xf bank_mask:0xf\n" \
        /* select this lane's column (kg&3) */ \
        "v_cndmask_b32 v30, v26, v27, %[m0]\n" \
        "v_cndmask_b32 v31, v28, v29, %[m0]\n" \
        "v_cndmask_b32 v30, v30, v31, %[m1]\n" \
        /* xi (pre-scaled, prefetched last step) */ \
        "s_waitcnt vmcnt(2)\n" \
        "v_add_f32 v30, v30, " XC "\n" \
        /* tanh = 1 - 2*rcp(exp2(arg)+1); arg already scaled by 2log2e */ \
        "v_exp_f32 v19, v30\n" \
        "s_nop 0\n" \
        "v_add_f32 v19, 1.0, v19\n" \
        "v_rcp_f32 v19, v19\n" \
        "s_nop 0\n" \
        "v_fma_f32 v30, -2.0, v19, 1.0\n" \
        /* masked LDS h write (kg<4 lanes only; no dummy-bank conflicts) */ \
        "s_and_saveexec_b64 s[84:85], %[msk]\n" \
        "ds_write_b32 v17, v30\n" \
        "s_mov_b64 exec, s[84:85]\n" \
        "v_xor_b32 v17, 0x800, v17\n" \
        /* global h store: all lanes, dup addrs merge */ \
        "global_store_dword v23, v30, %[iob]\n" \
        "v_add_u32 v23, 0x40000, v23\n" \
        "s_waitcnt lgkmcnt(0)\n" \
        "s_barrier\n"

#define SCALE_PAIR(P) "v_pk_mul_f32 v[" P "], v[" P "], v[26:27]\n"

__global__ __launch_bounds__(512, 2) void rec_kernel(
    const float* __restrict__ Wh, const float* __restrict__ h0,
    float* __restrict__ io)
{
    __shared__ float hbuf[864];  // buf0 [0,1152) buf1 [0x800,+1152)

    const int tid  = threadIdx.x;
    const int b    = blockIdx.x;
    const int lane = tid & 63;
    const int q    = tid >> 6;                       // wave id 0..7
    const int kg   = (lane & 3) | ((lane >> 1) & 4); // 0..7
    const int cg   = ((lane >> 2) & 1) | ((lane >> 3) & 6); // 0..7
    const int col0 = 32 * q + 4 * cg;
    const int col  = col0 + (kg & 3);                // finalize column

    const float* wp  = Wh + (size_t)col0 * HH + kg * 32;
    const float* iob = io + (size_t)b * HH;
    unsigned hbase = (unsigned)(size_t)&hbuf[0];
    unsigned hvr = hbase + kg * 144;                 // read base (buf0)
    unsigned hvw = hbase + 0x800 + q * 144 + (4 * cg + (kg & 3)) * 4;
    unsigned vio = (unsigned)(col * 4);
    unsigned viomax = vio + 511u * 0x40000u;         // last valid xi plane
    unsigned long long m0 = __ballot((lane & 1) != 0);
    unsigned long long m1 = __ballot((lane & 2) != 0);
    unsigned long long msk = __ballot(kg < 4);       // LDS-writer lanes

    if (tid < HH) hbuf[(tid >> 5) * 36 + (tid & 31)] = h0[(size_t)b * HH + tid];
    __syncthreads();

    asm volatile(
        // ---- Wh fragment: w[j][m] -> v[72+32j+4m] ----
        "global_load_dwordx4 v[72:75],   %[wp], off\n"
        "global_load_dwordx4 v[76:79],   %[wp], off offset:16\n"
        "global_load_dwordx4 v[80:83],   %[wp], off offset:32\n"
        "global_load_dwordx4 v[84:87],   %[wp], off offset:48\n"
        "global_load_dwordx4 v[88:91],   %[wp], off offset:64\n"
        "global_load_dwordx4 v[92:95],   %[wp], off offset:80\n"
        "global_load_dwordx4 v[96:99],   %[wp], off offset:96\n"
        "global_load_dwordx4 v[100:103], %[wp], off offset:112\n"
        "global_load_dwordx4 v[104:107], %[wp], off offset:1024\n"
        "global_load_dwordx4 v[108:111], %[wp], off offset:1040\n"
        "global_load_dwordx4 v[112:115], %[wp], off offset:1056\n"
        "global_load_dwordx4 v[116:119], %[wp], off offset:1072\n"
        "global_load_dwordx4 v[120:123], %[wp], off offset:1088\n"
        "global_load_dwordx4 v[124:127], %[wp], off offset:1104\n"
        "global_load_dwordx4 v[128:131], %[wp], off offset:1120\n"
        "global_load_dwordx4 v[132:135], %[wp], off offset:1136\n"
        "global_load_dwordx4 v[136:139], %[wp], off offset:2048\n"
        "global_load_dwordx4 v[140:143], %[wp], off offset:2064\n"
        "global_load_dwordx4 v[144:147], %[wp], off offset:2080\n"
        "global_load_dwordx4 v[148:151], %[wp], off offset:2096\n"
        "global_load_dwordx4 v[152:155], %[wp], off offset:2112\n"
        "global_load_dwordx4 v[156:159], %[wp], off offset:2128\n"
        "global_load_dwordx4 v[160:163], %[wp], off offset:2144\n"
        "global_load_dwordx4 v[164:167], %[wp], off offset:2160\n"
        "global_load_dwordx4 v[168:171], %[wp], off offset:3072\n"
        "global_load_dwordx4 v[172:175], %[wp], off offset:3088\n"
        "global_load_dwordx4 v[176:179], %[wp], off offset:3104\n"
        "global_load_dwordx4 v[180:183], %[wp], off offset:3120\n"
        "global_load_dwordx4 v[184:187], %[wp], off offset:3136\n"
        "global_load_dwordx4 v[188:191], %[wp], off offset:3152\n"
        "global_load_dwordx4 v[192:195], %[wp], off offset:3168\n"
        "global_load_dwordx4 v[196:199], %[wp], off offset:3184\n"
        // ---- init + xi_0 prologue load ----
        "v_mov_b32 v16, %[hvr]\n"
        "v_mov_b32 v17, %[hvw]\n"
        "v_mov_b32 v18, %[vio]\n"
        "v_mov_b32 v23, %[vio]\n"
        "global_load_dword v21, v18, %[iob]\n"
        "v_add_u32 v18, 0x40000, v18\n"
        "s_movk_i32 s82, 0x100\n"
        "s_waitcnt vmcnt(0)\n"
        // ---- one-time pre-scale of Wh fragment by 2*log2(e) ----
        "v_mov_b32 v26, 0x4038aa3b\n"
        "v_mov_b32 v27, 0x4038aa3b\n"
        SCALE_PAIR("72:73")   SCALE_PAIR("74:75")   SCALE_PAIR("76:77")   SCALE_PAIR("78:79")
        SCALE_PAIR("80:81")   SCALE_PAIR("82:83")   SCALE_PAIR("84:85")   SCALE_PAIR("86:87")
        SCALE_PAIR("88:89")   SCALE_PAIR("90:91")   SCALE_PAIR("92:93")   SCALE_PAIR("94:95")
        SCALE_PAIR("96:97")   SCALE_PAIR("98:99")   SCALE_PAIR("100:101") SCALE_PAIR("102:103")
        SCALE_PAIR("104:105") SCALE_PAIR("106:107") SCALE_PAIR("108:109") SCALE_PAIR("110:111")
        SCALE_PAIR("112:113") SCALE_PAIR("114:115") SCALE_PAIR("116:117") SCALE_PAIR("118:119")
        SCALE_PAIR("120:121") SCALE_PAIR("122:123") SCALE_PAIR("124:125") SCALE_PAIR("126:127")
        SCALE_PAIR("128:129") SCALE_PAIR("130:131") SCALE_PAIR("132:133") SCALE_PAIR("134:135")
        SCALE_PAIR("136:137") SCALE_PAIR("138:139") SCALE_PAIR("140:141") SCALE_PAIR("142:143")
        SCALE_PAIR("144:145") SCALE_PAIR("146:147") SCALE_PAIR("148:149") SCALE_PAIR("150:151")
        SCALE_PAIR("152:153") SCALE_PAIR("154:155") SCALE_PAIR("156:157") SCALE_PAIR("158:159")
        SCALE_PAIR("160:161") SCALE_PAIR("162:163") SCALE_PAIR("164:165") SCALE_PAIR("166:167")
        SCALE_PAIR("168:169") SCALE_PAIR("170:171") SCALE_PAIR("172:173") SCALE_PAIR("174:175")
        SCALE_PAIR("176:177") SCALE_PAIR("178:179") SCALE_PAIR("180:181") SCALE_PAIR("182:183")
        SCALE_PAIR("184:185") SCALE_PAIR("186:187") SCALE_PAIR("188:189") SCALE_PAIR("190:191")
        SCALE_PAIR("192:193") SCALE_PAIR("194:195") SCALE_PAIR("196:197") SCALE_PAIR("198:199")
        "LTOP_%=:\n"
        RNN_BODY("v20", "v21")
        RNN_BODY("v21", "v20")
        "s_sub_u32 s82, s82, 1\n"
        "s_cmp_lg_u32 s82, 0\n"
        "s_cbranch_scc1 LTOP_%=\n"
        :
        : [wp] "v"(wp), [iob] "s"(iob),
          [hvr] "v"(hvr), [hvw] "v"(hvw), [vio] "v"(vio),
          [viomax] "v"(viomax), [m0] "s"(m0), [m1] "s"(m1), [msk] "s"(msk)
        : "memory", "scc", "s82", "s84", "s85",
          "v16","v17","v18","v19","v20","v21","v22","v23",
          "v24","v25","v26","v27","v28","v29","v30","v31",
          "v32","v33","v34","v35","v36","v37","v38","v39",
          "v40","v41","v42","v43","v44","v45","v46","v47",
          "v48","v49","v50","v51","v52","v53","v54","v55",
          "v56","v57","v58","v59","v60","v61","v62","v63",
          "v64","v65","v66","v67","v68","v69","v70","v71",
          "v72","v73","v74","v75","v76","v77","v78","v79",
          "v80","v81","v82","v83","v84","v85","v86","v87",
          "v88","v89","v90","v91","v92","v93","v94","v95",
          "v96","v97","v98","v99","v100","v101","v102","v103",
          "v104","v105","v106","v107","v108","v109","v110","v111",
          "v112","v113","v114","v115","v116","v117","v118","v119",
          "v120","v121","v122","v123","v124","v125","v126","v127",
          "v128","v129","v130","v131","v132","v133","v134","v135",
          "v136","v137","v138","v139","v140","v141","v142","v143",
          "v144","v145","v146","v147","v148","v149","v150","v151",
          "v152","v153","v154","v155","v156","v157","v158","v159",
          "v160","v161","v162","v163","v164","v165","v166","v167",
          "v168","v169","v170","v171","v172","v173","v174","v175",
          "v176","v177","v178","v179","v180","v181","v182","v183",
          "v184","v185","v186","v187","v188","v189","v190","v191",
          "v192","v193","v194","v195","v196","v197","v198","v199");
}

extern "C" void kernel_launch(void* const* d_in, const int* in_sizes, int n_in,
                              void* d_out, int out_size, void* d_ws, size_t ws_size,
                              hipStream_t stream) {
    const float* x  = (const float*)d_in[0];  // [T,B,I]
    const float* h0 = (const float*)d_in[1];  // [B,H]
    const float* Wi = (const float*)d_in[2];  // [H,I]
    const float* Wh = (const float*)d_in[3];  // [H,H]
    const float* bh = (const float*)d_in[4];  // [H]
    float* out = (float*)d_out;               // [T,B,H]

    dim3 pgrid(TT * BB / 64, HH / 64);
    proj_kernel<<<pgrid, 256, 0, stream>>>(x, Wi, bh, out);
    rec_kernel<<<BB, 512, 0, stream>>>(Wh, h0, out);
}